// Round 1
// baseline (132.673 us; speedup 1.0000x reference)
//
#include <hip/hip_runtime.h>
#include <hip/hip_bf16.h>

// SparseDynamicConv3d: out[n,o] = sum_k sum_c feat[idx[k,n],c] * W[k,c,o]
// Round 7: grid is 4.77% occupied -> only ~2.24 valid taps/voxel. Restructure:
//  - no featb: gather fp32 feat directly, fp32->bf16 convert in-register
//    (prep shrinks from 3450 to 325 blocks; ~32 MB of prep traffic removed)
//  - no LDS, no barriers: B-fragments read straight from 166 KB L1/L2-resident
//    wtb (old design spent ~12.4 us/CU on the LDS pipe just delivering B)
//  - M=64 rows/wave (2 row-groups) halves per-row B traffic; 782x128 grid
//  - wave-uniform skip of taps with no valid voxel in either group
#define NVOX       100000
#define INC        48
#define INC_MAX    64
#define OUTC       64
#define OUTC_MAX   96
#define KOFF       27
#define WTB_K      3072                      // shorts per k: 48x64, frag-packed
#define WTB_ELEMS  (KOFF * WTB_K)            // 82944
#define ZROW_FLOATS 48
#define WS_NEED    ((size_t)WTB_ELEMS * 2 + ZROW_FLOATS * 4)   // 166080 B
#define WTB_PREP_BLKS  (WTB_ELEMS / 256)     // 324 exact
#define MAIN_BLOCKS 782                      // 782 blocks * 128 rows = 100096

typedef __attribute__((ext_vector_type(8)))  short short8;
typedef __attribute__((ext_vector_type(4)))  float floatx4;
typedef __attribute__((ext_vector_type(16))) float floatx16;

__device__ __forceinline__ short f2bf(float f) {
    union { __hip_bfloat16 h; short s; } u;
    u.h = __float2bfloat16(f);
    return u.s;
}

// wtb: frag-packed per k as 384 16B chunks: chunk = (ks*2+nt)*64 + lane,
//      element j: B[c = ks*16 + (lane>>5)*8 + j][o = nt*32 + (lane&31)]
//      (32x32x16 B-operand layout, verified in rounds 1-6).
// zrowf: 48 zero floats — gather target for idx<0 lanes.
__global__ void __launch_bounds__(256)
prep_w(const float* __restrict__ wk, short* __restrict__ wtb,
       float* __restrict__ zrowf)
{
    int b = blockIdx.x;
    if (b < WTB_PREP_BLKS) {
        int t = b * 256 + threadIdx.x;       // < 82944 exact
        int k = t / WTB_K, r = t % WTB_K;
        int chunk = r >> 3, j = r & 7;
        int f = chunk >> 6, lane = chunk & 63;
        int ks = f >> 1, nt = f & 1;
        int c = ks * 16 + (lane >> 5) * 8 + j;      // 0..47, K=48 exact
        int o = nt * 32 + (lane & 31);
        wtb[t] = f2bf(wk[k * (INC_MAX * OUTC_MAX) + c * OUTC_MAX + o]);
    } else if (threadIdx.x < ZROW_FLOATS) {
        zrowf[threadIdx.x] = 0.f;
    }
}

__global__ void __launch_bounds__(128, 2)
spconv_main(const float* __restrict__ feat, const short* __restrict__ wtb,
            const float* __restrict__ zrowf, const int* __restrict__ idx,
            float* __restrict__ out)
{
    const int tid  = threadIdx.x;
    const int lane = tid & 63;
    const int wave = tid >> 6;
    const int l32  = lane & 31;
    const int hi   = lane >> 5;      // 0/1: which 8-channel half this lane holds

    // XCD-contiguous swizzle (bijective for bid<776, identity tail)
    int bid = blockIdx.x;
    int sb  = (bid < 776) ? ((bid & 7) * 97 + (bid >> 3)) : bid;

    const int m0 = (sb * 2 + wave) * 64;       // 64 rows per wave
    if (m0 >= NVOX) return;                    // only last wave (rows 100032+)
    const bool act1 = (m0 + 32) < NVOX;        // NVOX % 32 == 0
    const int r0 = m0 + l32;
    const int r1 = act1 ? (m0 + 32 + l32) : 0;

    floatx16 acc[2][2];                        // [group][nt]
    #pragma unroll
    for (int g = 0; g < 2; ++g)
        #pragma unroll
        for (int nt = 0; nt < 2; ++nt)
            #pragma unroll
            for (int r = 0; r < 16; ++r) acc[g][nt][r] = 0.f;

    int t0 = idx[r0];                          // k = 0
    int t1 = act1 ? idx[r1] : -1;

    #pragma unroll 1
    for (int k = 0; k < KOFF; ++k) {
        // prefetch next tap's idx (consumed at next iteration's ballot;
        // latency hidden under this tap's loads + MFMAs)
        int n0 = -1, n1 = -1;
        if (k + 1 < KOFF) {
            n0 = idx[(k + 1) * NVOX + r0];
            if (act1) n1 = idx[(k + 1) * NVOX + r1];
        }
        const bool v0 = (t0 >= 0), v1 = (t1 >= 0);
        if (__any(v0 || v1)) {
            const float* a0p = v0 ? (feat + t0 * INC) : zrowf;   // 16B aligned
            const float* a1p = v1 ? (feat + t1 * INC) : zrowf;

            // B fragments straight from global (L1/L2-resident stream)
            const short8* bp = (const short8*)(wtb + k * WTB_K);
            short8 bw[3][2];
            #pragma unroll
            for (int ks = 0; ks < 3; ++ks) {
                bw[ks][0] = bp[ks * 128 + lane];
                bw[ks][1] = bp[ks * 128 + 64 + lane];
            }
            // fp32 A gather: 8 channels (c = ks*16 + hi*8 + j) per frag
            floatx4 f0[3][2], f1[3][2];
            #pragma unroll
            for (int ks = 0; ks < 3; ++ks) {
                const floatx4* p0 = (const floatx4*)(a0p + ks * 16 + hi * 8);
                const floatx4* p1 = (const floatx4*)(a1p + ks * 16 + hi * 8);
                f0[ks][0] = p0[0]; f0[ks][1] = p0[1];
                f1[ks][0] = p1[0]; f1[ks][1] = p1[1];
            }
            #pragma unroll
            for (int ks = 0; ks < 3; ++ks) {
                short8 a0, a1;
                #pragma unroll
                for (int j = 0; j < 4; ++j) {
                    a0[j]     = f2bf(f0[ks][0][j]);
                    a0[4 + j] = f2bf(f0[ks][1][j]);
                    a1[j]     = f2bf(f1[ks][0][j]);
                    a1[4 + j] = f2bf(f1[ks][1][j]);
                }
                acc[0][0] = __builtin_amdgcn_mfma_f32_32x32x16_bf16(a0, bw[ks][0], acc[0][0], 0, 0, 0);
                acc[0][1] = __builtin_amdgcn_mfma_f32_32x32x16_bf16(a0, bw[ks][1], acc[0][1], 0, 0, 0);
                acc[1][0] = __builtin_amdgcn_mfma_f32_32x32x16_bf16(a1, bw[ks][0], acc[1][0], 0, 0, 0);
                acc[1][1] = __builtin_amdgcn_mfma_f32_32x32x16_bf16(a1, bw[ks][1], acc[1][1], 0, 0, 0);
            }
        }
        t0 = n0; t1 = n1;
    }

    // epilogue: D col = nt*32 + l32, row = (r&3) + 8*(r>>2) + 4*hi
    #pragma unroll
    for (int nt = 0; nt < 2; ++nt)
        #pragma unroll
        for (int r = 0; r < 16; ++r) {
            int row = (r & 3) + 8 * (r >> 2) + 4 * hi;
            out[(m0 + row) * OUTC + nt * 32 + l32] = acc[0][nt][r];
        }
    if (act1) {
        #pragma unroll
        for (int nt = 0; nt < 2; ++nt)
            #pragma unroll
            for (int r = 0; r < 16; ++r) {
                int row = (r & 3) + 8 * (r >> 2) + 4 * hi;
                out[(m0 + 32 + row) * OUTC + nt * 32 + l32] = acc[1][nt][r];
            }
    }
}

// Safety fallback (only if workspace were too small): plain fp32.
__global__ void __launch_bounds__(256)
spconv_fallback(const float* __restrict__ feat, const float* __restrict__ wk,
                const int* __restrict__ idx, float* __restrict__ out)
{
    int t = blockIdx.x * 256 + threadIdx.x;
    if (t >= NVOX * OUTC) return;
    int n = t >> 6, o = t & 63;
    float s = 0.f;
    for (int k = 0; k < KOFF; ++k) {
        int g = idx[k * NVOX + n];
        if (g >= 0) {
            const float* fr = feat + g * INC;
            const float* wr = wk + k * (INC_MAX * OUTC_MAX) + o;
            #pragma unroll 8
            for (int c = 0; c < INC; ++c) s += fr[c] * wr[c * OUTC_MAX];
        }
    }
    out[t] = s;
}

extern "C" void kernel_launch(void* const* d_in, const int* in_sizes, int n_in,
                              void* d_out, int out_size, void* d_ws, size_t ws_size,
                              hipStream_t stream) {
    const float* feat = (const float*)d_in[0];
    const float* wk   = (const float*)d_in[1];
    const int*   idx  = (const int*)d_in[2];
    float* out = (float*)d_out;

    if (ws_size >= WS_NEED) {
        short* wtb   = (short*)d_ws;
        float* zrowf = (float*)((char*)d_ws + (size_t)WTB_ELEMS * 2);
        prep_w<<<WTB_PREP_BLKS + 1, 256, 0, stream>>>(wk, wtb, zrowf);
        spconv_main<<<MAIN_BLOCKS, 128, 0, stream>>>(feat, wtb, zrowf, idx, out);
    } else {
        spconv_fallback<<<(NVOX * OUTC + 255) / 256, 256, 0, stream>>>(feat, wk, idx, out);
    }
}

// Round 2
// 110.403 us; speedup vs baseline: 1.2017x; 1.2017x over previous
//
#include <hip/hip_runtime.h>
#include <hip/hip_bf16.h>

// SparseDynamicConv3d: out[n,o] = sum_k sum_c feat[idx[k,n],c] * W[k,c,o]
// Round 8: round-6 skeleton restored (256thr, M=32/wave, LDS B pipeline,
// 12 waves/CU — round 7's global-B + 6-waves/CU variant was latency-bound,
// main 13->62us). New vs round 6:
//  - featb prep eliminated: gather fp32 feat directly into an F-reg ring,
//    fp32->bf16 cvt deferred to compute (no early waitcnt, same prefetch
//    depth). Saves ~32 MB prep traffic / ~7 us. Bit-identical numerics.
//  - wave-uniform tap skip (grid 4.77% occupied -> ~21% of taps have no
//    valid row among a wave's 32): skips 6 ds_read + 6 MFMA + 6 gathers.
//    B staging + barriers stay unconditional -> round-6 LDS schedule intact.
#define NVOX       100000
#define INC        48
#define INC_MAX    64
#define OUTC       64
#define OUTC_MAX   96
#define KOFF       27
#define WTB_K      3072                      // shorts per k: 48x64, frag-packed
#define WTB_ELEMS  (KOFF * WTB_K)            // 82944
#define ZROW_FLOATS 48
#define WS_NEED    ((size_t)WTB_ELEMS * 2 + ZROW_FLOATS * 4)   // 166080 B
#define WTB_PREP_BLKS  (WTB_ELEMS / 256)     // 324 exact
#define MAIN_BLOCKS 782                      // 3125 waves of 32 rows, +3 idle

typedef __attribute__((ext_vector_type(8)))  short short8;
typedef __attribute__((ext_vector_type(4)))  float floatx4;
typedef __attribute__((ext_vector_type(16))) float floatx16;

__device__ __forceinline__ short f2bf(float f) {
    union { __hip_bfloat16 h; short s; } u;
    u.h = __float2bfloat16(f);
    return u.s;
}

// wtb: frag-packed per k as 384 16B chunks: chunk = (ks*2+nt)*64 + lane,
//      element j: B[c = ks*16 + (lane>>5)*8 + j][o = nt*32 + (lane&31)]
//      (32x32x16 B-operand layout, verified rounds 1-6).
// zrowf: 48 zero floats — gather target for idx<0 lanes.
__global__ void __launch_bounds__(256)
prep_w(const float* __restrict__ wk, short* __restrict__ wtb,
       float* __restrict__ zrowf)
{
    int b = blockIdx.x;
    if (b < WTB_PREP_BLKS) {
        int t = b * 256 + threadIdx.x;       // < 82944 exact
        int k = t / WTB_K, r = t % WTB_K;
        int chunk = r >> 3, j = r & 7;
        int f = chunk >> 6, lane = chunk & 63;
        int ks = f >> 1, nt = f & 1;
        int c = ks * 16 + (lane >> 5) * 8 + j;      // 0..47, K=48 exact
        int o = nt * 32 + (lane & 31);
        wtb[t] = f2bf(wk[k * (INC_MAX * OUTC_MAX) + c * OUTC_MAX + o]);
    } else if (threadIdx.x < ZROW_FLOATS) {
        zrowf[threadIdx.x] = 0.f;
    }
}

__global__ void __launch_bounds__(256, 3)
spconv_main(const float* __restrict__ feat, const short* __restrict__ wtb,
            const float* __restrict__ zrowf, const int* __restrict__ idx,
            float* __restrict__ out)
{
    __shared__ short Bs[4][WTB_K];   // 4 x 6KB single-k B buffers

    const int tid  = threadIdx.x;
    const int lane = tid & 63;
    const int wave = tid >> 6;
    const int l32  = lane & 31;
    const int hi   = lane >> 5;      // 0/1: which 8-channel half this lane holds

    // XCD-contiguous swizzle (bijective for bid<776, identity tail)
    int bid = blockIdx.x;
    int sb  = (bid < 776) ? ((bid & 7) * 97 + (bid >> 3)) : bid;

    const int m0   = (sb * 4 + wave) * 32;     // 32 rows per wave
    const bool act = (m0 < NVOX);              // whole-wave validity (NVOX%32==0)
    const int rr   = act ? (m0 + l32) : 0;     // this lane's voxel row

    floatx16 acc[2];
    #pragma unroll
    for (int nt = 0; nt < 2; ++nt)
        #pragma unroll
        for (int r = 0; r < 16; ++r) acc[nt][r] = 0.f;

    floatx4 F[2][3][2];  // [k&1][ks][half] fp32 A-row ring (cvt deferred)
    short8  bst[2][2];   // [k&1][half] B-stage ring (half 1 only for tid<128)
    int     rowg[4];     // [k&3] gathered row (idx<0 -> zrowf)
    bool    va4[4];      // [k&3] wave-level tap validity (set at ldrow)
    bool    ca[2];       // [k&1] compute guard (captured at aload; va4[k&3]
                         // is clobbered by ldrow(k+4) before compute(k))

    auto ldrow = [&](int k) {
        int t0 = idx[k * NVOX + rr];
        rowg[k & 3] = t0;
        va4[k & 3] = __any(t0 >= 0);
    };
    auto aload = [&](int k) {
        bool v = va4[k & 3];
        ca[k & 1] = v;
        if (v) {
            int t = rowg[k & 3];
            const float* p = (t >= 0) ? (feat + (size_t)t * INC) : zrowf;
            #pragma unroll
            for (int ks = 0; ks < 3; ++ks) {
                const floatx4* q = (const floatx4*)(p + ks * 16 + hi * 8);
                F[k & 1][ks][0] = q[0];
                F[k & 1][ks][1] = q[1];
            }
        }
    };
    auto bload = [&](int k) {
        bst[k & 1][0] = *(const short8*)(wtb + k * WTB_K + tid * 8);
        if (tid < 128)
            bst[k & 1][1] = *(const short8*)(wtb + k * WTB_K + 2048 + tid * 8);
    };
    auto compute = [&](int k) {
        if (!ca[k & 1]) return;
        #pragma unroll
        for (int ks = 0; ks < 3; ++ks) {
            short8 b0 = *(const short8*)&Bs[k & 3][(ks * 128 + lane) * 8];
            short8 b1 = *(const short8*)&Bs[k & 3][(ks * 128 + 64 + lane) * 8];
            short8 a;
            #pragma unroll
            for (int j = 0; j < 4; ++j) {
                a[j]     = f2bf(F[k & 1][ks][0][j]);
                a[4 + j] = f2bf(F[k & 1][ks][1][j]);
            }
            acc[0] = __builtin_amdgcn_mfma_f32_32x32x16_bf16(a, b0, acc[0], 0, 0, 0);
            acc[1] = __builtin_amdgcn_mfma_f32_32x32x16_bf16(a, b1, acc[1], 0, 0, 0);
        }
    };

    // ---- prologue ----
    ldrow(0); ldrow(1); ldrow(2); ldrow(3);
    bload(0); bload(1);
    aload(0); aload(1);

    #pragma unroll
    for (int j = 0; j < 14; ++j) {
        const int kk = 2 * j;

        // commit staged B(kk), B(kk+1) regs to LDS buffers kk&3, (kk+1)&3
        *(short8*)&Bs[kk & 3][tid * 8] = bst[0][0];
        if (tid < 128) *(short8*)&Bs[kk & 3][2048 + tid * 8] = bst[0][1];
        if (kk + 1 < KOFF) {
            *(short8*)&Bs[(kk + 1) & 3][tid * 8] = bst[1][0];
            if (tid < 128) *(short8*)&Bs[(kk + 1) & 3][2048 + tid * 8] = bst[1][1];
        }
        __syncthreads();

        // stage next pair's B into regs; idx two pairs ahead
        if (kk + 2 < KOFF) bload(kk + 2);
        if (kk + 3 < KOFF) bload(kk + 3);
        if (kk + 4 < KOFF) ldrow(kk + 4);
        if (kk + 5 < KOFF) ldrow(kk + 5);

        compute(kk);
        if (kk + 2 < KOFF) aload(kk + 2);     // refills F[kk&1] after use
        if (kk + 1 < KOFF) {
            compute(kk + 1);
            if (kk + 3 < KOFF) aload(kk + 3);
        }
    }

    // ---- epilogue: D col = nt*32 + (lane&31), row = (r&3) + 8*(r>>2) + 4*hi ----
    if (act) {
        #pragma unroll
        for (int nt = 0; nt < 2; ++nt) {
            #pragma unroll
            for (int r = 0; r < 16; ++r) {
                int row = (r & 3) + 8 * (r >> 2) + 4 * hi;
                out[(m0 + row) * OUTC + nt * 32 + l32] = acc[nt][r];
            }
        }
    }
}

// Safety fallback (only if workspace were too small): plain fp32.
__global__ void __launch_bounds__(256)
spconv_fallback(const float* __restrict__ feat, const float* __restrict__ wk,
                const int* __restrict__ idx, float* __restrict__ out)
{
    int t = blockIdx.x * 256 + threadIdx.x;
    if (t >= NVOX * OUTC) return;
    int n = t >> 6, o = t & 63;
    float s = 0.f;
    for (int k = 0; k < KOFF; ++k) {
        int g = idx[k * NVOX + n];
        if (g >= 0) {
            const float* fr = feat + g * INC;
            const float* wr = wk + k * (INC_MAX * OUTC_MAX) + o;
            #pragma unroll 8
            for (int c = 0; c < INC; ++c) s += fr[c] * wr[c * OUTC_MAX];
        }
    }
    out[t] = s;
}

extern "C" void kernel_launch(void* const* d_in, const int* in_sizes, int n_in,
                              void* d_out, int out_size, void* d_ws, size_t ws_size,
                              hipStream_t stream) {
    const float* feat = (const float*)d_in[0];
    const float* wk   = (const float*)d_in[1];
    const int*   idx  = (const int*)d_in[2];
    float* out = (float*)d_out;

    if (ws_size >= WS_NEED) {
        short* wtb   = (short*)d_ws;
        float* zrowf = (float*)((char*)d_ws + (size_t)WTB_ELEMS * 2);
        prep_w<<<WTB_PREP_BLKS + 1, 256, 0, stream>>>(wk, wtb, zrowf);
        spconv_main<<<MAIN_BLOCKS, 256, 0, stream>>>(feat, wtb, zrowf, idx, out);
    } else {
        spconv_fallback<<<(NVOX * OUTC + 255) / 256, 256, 0, stream>>>(feat, wk, idx, out);
    }
}